// Round 6
// baseline (93.875 us; speedup 1.0000x reference)
//
#include <hip/hip_runtime.h>

// 4-qubit / 3-layer VQC, B = 2^20.
//
// Identity (verified R4/R5): with merged angle th_w = patch_w + params[0,w,0],
// each output is EXACTLY multilinear in t_w = (1, cos th_w, sin th_w):
//     o_w = sum T^w[a,b,c,d] t0_a t1_b t2_c t3_d
// Setup kernel simulates the batch-uniform remainder of the circuit on the
// 3^4 grid th in {0, pi/2, pi} and inverts the evaluation map -> T
// (4 x 81 floats, stored as (T0,T1)/(T2,T3) pairs for packed FMA).
//
// R6 vs R5: main kernel processes 4 elements per thread, interleaved in the
// fully-unrolled bilinear form -> each uniform s_load of a T pair feeds 8
// packed FMAs (was 2), quartering the per-element scalar-mem stalls; and
// v01[0]=v23[0]=1 is exploited to init accumulators from T directly.

typedef float v2f __attribute__((ext_vector_type(2)));

// ws layout: [0..161]   pairs (T0[pos], T1[pos]) for pos = 0..80
//            [162..323] pairs (T2[pos], T3[pos])
// pos = 9*(3*d0+d1) + (3*d2+d3), digit d in {0,1,2} <-> basis (1, cos, sin)
__global__ void vqc_setup(const float* __restrict__ params,
                          float* __restrict__ ws) {
    __shared__ float trig[12][4];   // (cy, sy, cz, sz) half-angle per (l,w)
    __shared__ float bufA[81][4];
    __shared__ float bufB[81][4];
    const int tid = threadIdx.x;

    if (tid < 12) {
        float s, c;
        __sincosf(0.5f * params[tid * 2 + 0], &s, &c);
        trig[tid][0] = c; trig[tid][1] = s;
        __sincosf(0.5f * params[tid * 2 + 1], &s, &c);
        trig[tid][2] = c; trig[tid][3] = s;
    }
    __syncthreads();

    if (tid < 81) {
        const int d0 = tid / 27, d1 = (tid / 9) % 3, d2 = (tid / 3) % 3, d3 = tid % 3;
        const float chalf[3] = {1.0f, 0.70710678118654752f, 0.0f};
        const float shalf[3] = {0.0f, 0.70710678118654752f, 1.0f};
        const float ch[4] = {chalf[d0], chalf[d1], chalf[d2], chalf[d3]};
        const float sh[4] = {shalf[d0], shalf[d1], shalf[d2], shalf[d3]};

        float re[16], im[16];
#pragma unroll
        for (int k = 0; k < 16; ++k) {
            float a = ((k >> 3) & 1) ? sh[0] : ch[0];
            a *= ((k >> 2) & 1) ? sh[1] : ch[1];
            a *= ((k >> 1) & 1) ? sh[2] : ch[2];
            a *= (k & 1) ? sh[3] : ch[3];
            re[k] = a; im[k] = 0.0f;
        }

        // ---- layer 0: RZ only (RY merged into grid angle) ----
#pragma unroll
        for (int w = 0; w < 4; ++w) {
            const int m = 8 >> w;
            const float cz = trig[w][2], sz = trig[w][3];
#pragma unroll
            for (int k = 0; k < 16; ++k) {
                const float r = re[k], q = im[k];
                if (k & m) { re[k] = r * cz - q * sz; im[k] = q * cz + r * sz; }
                else       { re[k] = r * cz + q * sz; im[k] = q * cz - r * sz; }
            }
        }
#pragma unroll
        for (int w = 0; w < 3; ++w) {
            const int cm = 8 >> w, tm = 4 >> w;
#pragma unroll
            for (int b = 0; b < 16; ++b) {
                if ((b & cm) && !(b & tm)) {
                    const int j = b | tm;
                    float t = re[b]; re[b] = re[j]; re[j] = t;
                    t = im[b]; im[b] = im[j]; im[j] = t;
                }
            }
        }

        // ---- layers 1, 2 (layer-2 RZ dropped: probability-invariant) ----
#pragma unroll
        for (int l = 1; l < 3; ++l) {
#pragma unroll
            for (int w = 0; w < 4; ++w) {
                const int m = 8 >> w, g = l * 4 + w;
                const float cy = trig[g][0], sy = trig[g][1];
#pragma unroll
                for (int b = 0; b < 16; ++b) {
                    if (b & m) continue;
                    const int j = b | m;
                    const float r0 = re[b], r1 = re[j];
                    const float i0 = im[b], i1 = im[j];
                    re[b] = cy * r0 - sy * r1;  re[j] = sy * r0 + cy * r1;
                    im[b] = cy * i0 - sy * i1;  im[j] = sy * i0 + cy * i1;
                }
                if (l != 2) {
                    const float cz = trig[g][2], sz = trig[g][3];
#pragma unroll
                    for (int k = 0; k < 16; ++k) {
                        const float r = re[k], q = im[k];
                        if (k & m) { re[k] = r * cz - q * sz; im[k] = q * cz + r * sz; }
                        else       { re[k] = r * cz + q * sz; im[k] = q * cz - r * sz; }
                    }
                }
            }
#pragma unroll
            for (int w = 0; w < 3; ++w) {
                const int cm = 8 >> w, tm = 4 >> w;
#pragma unroll
                for (int b = 0; b < 16; ++b) {
                    if ((b & cm) && !(b & tm)) {
                        const int j = b | tm;
                        float t = re[b]; re[b] = re[j]; re[j] = t;
                        t = im[b]; im[b] = im[j]; im[j] = t;
                    }
                }
            }
        }

        float ev0 = 0.f, ev1 = 0.f, ev2 = 0.f, ev3 = 0.f;
#pragma unroll
        for (int k = 0; k < 16; ++k) {
            const float pk = re[k] * re[k] + im[k] * im[k];
            ev0 += (k & 8) ? -pk : pk;
            ev1 += (k & 4) ? -pk : pk;
            ev2 += (k & 2) ? -pk : pk;
            ev3 += (k & 1) ? -pk : pk;
        }
        bufA[tid][0] = ev0; bufA[tid][1] = ev1;
        bufA[tid][2] = ev2; bufA[tid][3] = ev3;
    }
    __syncthreads();

    // ---- invert evaluation map mode-by-mode ----
    // nodes {0, pi/2, pi} -> rows (1,1,0),(1,0,1),(1,-1,0);
    // Minv = [[.5,0,.5],[.5,0,-.5],[-.5,1,-.5]]
    const float Minv[3][3] = {{0.5f, 0.0f, 0.5f},
                              {0.5f, 0.0f, -0.5f},
                              {-0.5f, 1.0f, -0.5f}};
    const int strides[4] = {27, 9, 3, 1};
#pragma unroll
    for (int mo = 0; mo < 4; ++mo) {
        const int st = strides[mo];
        float (*src)[4] = (mo & 1) ? bufB : bufA;
        float (*dst)[4] = (mo & 1) ? bufA : bufB;
        for (int idx = tid; idx < 324; idx += blockDim.x) {
            const int w = idx & 3, pos = idx >> 2;
            const int dm = (pos / st) % 3;
            const int base = pos - dm * st;
            const float v = Minv[dm][0] * src[base][w]
                          + Minv[dm][1] * src[base + st][w]
                          + Minv[dm][2] * src[base + 2 * st][w];
            if (mo == 3) {
                const int half = (w >> 1);
                ws[half * 162 + pos * 2 + (w & 1)] = v;
            } else {
                dst[pos][w] = v;
            }
        }
        __syncthreads();
    }
}

#define EPT 4   // elements per thread

__global__ __launch_bounds__(256) void vqc_main(const float* __restrict__ patch,
                                                const float* __restrict__ params,
                                                const float* __restrict__ ws,
                                                float* __restrict__ out,
                                                const int B) {
    const int tid = threadIdx.x;
    const int base = blockIdx.x * (256 * EPT) + tid;

    const v2f* __restrict__ TA = reinterpret_cast<const v2f*>(ws);        // (T0,T1)
    const v2f* __restrict__ TB = reinterpret_cast<const v2f*>(ws + 162);  // (T2,T3)

    float v01[EPT][9], v23[EPT][9];
    bool act[EPT];

#pragma unroll
    for (int e = 0; e < EPT; ++e) {
        const int i = base + e * 256;
        act[e] = (i < B);
        const float4 p = act[e] ? reinterpret_cast<const float4*>(patch)[i]
                                : make_float4(0.f, 0.f, 0.f, 0.f);
        float c0, s0, c1, s1, c2, s2, c3, s3;
        __sincosf(p.x + params[0], &s0, &c0);
        __sincosf(p.y + params[2], &s1, &c1);
        __sincosf(p.z + params[4], &s2, &c2);
        __sincosf(p.w + params[6], &s3, &c3);
        v01[e][0] = 1.0f; v01[e][1] = c1;      v01[e][2] = s1;
        v01[e][3] = c0;   v01[e][4] = c0 * c1; v01[e][5] = c0 * s1;
        v01[e][6] = s0;   v01[e][7] = s0 * c1; v01[e][8] = s0 * s1;
        v23[e][0] = 1.0f; v23[e][1] = c3;      v23[e][2] = s3;
        v23[e][3] = c2;   v23[e][4] = c2 * c3; v23[e][5] = c2 * s3;
        v23[e][6] = s2;   v23[e][7] = s2 * c3; v23[e][8] = s2 * s3;
    }

    v2f o01[EPT], o23[EPT];

#pragma unroll
    for (int a = 0; a < 9; ++a) {
        v2f y01[EPT], y23[EPT];
        const v2f ta0 = TA[9 * a];       // b = 0 term: v23[0] == 1
        const v2f tb0 = TB[9 * a];
#pragma unroll
        for (int e = 0; e < EPT; ++e) { y01[e] = ta0; y23[e] = tb0; }
#pragma unroll
        for (int b = 1; b < 9; ++b) {
            const v2f ta = TA[9 * a + b];
            const v2f tb = TB[9 * a + b];
#pragma unroll
            for (int e = 0; e < EPT; ++e) {
                y01[e] += ta * v23[e][b];   // v_pk_fma_f32
                y23[e] += tb * v23[e][b];
            }
        }
        if (a == 0) {
            // v01[*][0] == 1
#pragma unroll
            for (int e = 0; e < EPT; ++e) { o01[e] = y01[e]; o23[e] = y23[e]; }
        } else {
#pragma unroll
            for (int e = 0; e < EPT; ++e) {
                o01[e] += v01[e][a] * y01[e];
                o23[e] += v01[e][a] * y23[e];
            }
        }
    }

#pragma unroll
    for (int e = 0; e < EPT; ++e) {
        const int i = base + e * 256;
        if (act[e])
            reinterpret_cast<float4*>(out)[i] =
                make_float4(o01[e].x, o01[e].y, o23[e].x, o23[e].y);
    }
}

extern "C" void kernel_launch(void* const* d_in, const int* in_sizes, int n_in,
                              void* d_out, int out_size, void* d_ws, size_t ws_size,
                              hipStream_t stream) {
    const float* patch  = (const float*)d_in[0];
    const float* params = (const float*)d_in[1];
    float* out = (float*)d_out;
    float* ws  = (float*)d_ws;
    const int B = in_sizes[0] / 4;

    vqc_setup<<<1, 128, 0, stream>>>(params, ws);

    const int per_block = 256 * EPT;
    const int grid = (B + per_block - 1) / per_block;
    vqc_main<<<grid, 256, 0, stream>>>(patch, params, ws, out, B);
}

// Round 7
// 80.195 us; speedup vs baseline: 1.1706x; 1.1706x over previous
//
#include <hip/hip_runtime.h>
#include <cstdint>

// 4-qubit / 3-layer VQC, B = 2^20.
//
// Identity (verified R4/R5): with merged angle th_w = patch_w + params[0,w,0],
// each output is EXACTLY multilinear in t_w = (1, cos th_w, sin th_w):
//     o_w = sum T^w[a,b,c,d] t0_a t1_b t2_c t3_d
// Setup kernel simulates the batch-uniform remainder of the circuit on the
// 3^4 grid th in {0, pi/2, pi} and inverts the evaluation map -> T
// (4 x 81 floats, stored as (T0,T1)/(T2,T3) pairs for packed FMA).
//
// R7 vs R5 (R6's EPT=4 regressed -> reverted to EPT=1):
//  - T and param offsets read through a constant-address-space (AS4) pointer
//    (cast via uintptr_t, composable_kernel-style). Uniform AS4 loads select
//    to s_load on the scalar pipe: removes ~162 per-wave VMEM issues + vmcnt
//    stalls; coefficients become SGPR operands of the FMAs.
//  - v01[0]=v23[0]=1 shortcuts kept from R6.

typedef float v2f __attribute__((ext_vector_type(2)));
typedef const v2f __attribute__((address_space(4))) cv2f;
typedef const float __attribute__((address_space(4))) cfloat;

// ws layout: [0..161]   pairs (T0[pos], T1[pos]) for pos = 0..80
//            [162..323] pairs (T2[pos], T3[pos])
// pos = 9*(3*d0+d1) + (3*d2+d3), digit d in {0,1,2} <-> basis (1, cos, sin)
__global__ void vqc_setup(const float* __restrict__ params,
                          float* __restrict__ ws) {
    __shared__ float trig[12][4];   // (cy, sy, cz, sz) half-angle per (l,w)
    __shared__ float bufA[81][4];
    __shared__ float bufB[81][4];
    const int tid = threadIdx.x;

    if (tid < 12) {
        float s, c;
        __sincosf(0.5f * params[tid * 2 + 0], &s, &c);
        trig[tid][0] = c; trig[tid][1] = s;
        __sincosf(0.5f * params[tid * 2 + 1], &s, &c);
        trig[tid][2] = c; trig[tid][3] = s;
    }
    __syncthreads();

    if (tid < 81) {
        const int d0 = tid / 27, d1 = (tid / 9) % 3, d2 = (tid / 3) % 3, d3 = tid % 3;
        const float chalf[3] = {1.0f, 0.70710678118654752f, 0.0f};
        const float shalf[3] = {0.0f, 0.70710678118654752f, 1.0f};
        const float ch[4] = {chalf[d0], chalf[d1], chalf[d2], chalf[d3]};
        const float sh[4] = {shalf[d0], shalf[d1], shalf[d2], shalf[d3]};

        float re[16], im[16];
#pragma unroll
        for (int k = 0; k < 16; ++k) {
            float a = ((k >> 3) & 1) ? sh[0] : ch[0];
            a *= ((k >> 2) & 1) ? sh[1] : ch[1];
            a *= ((k >> 1) & 1) ? sh[2] : ch[2];
            a *= (k & 1) ? sh[3] : ch[3];
            re[k] = a; im[k] = 0.0f;
        }

        // ---- layer 0: RZ only (RY merged into grid angle) ----
#pragma unroll
        for (int w = 0; w < 4; ++w) {
            const int m = 8 >> w;
            const float cz = trig[w][2], sz = trig[w][3];
#pragma unroll
            for (int k = 0; k < 16; ++k) {
                const float r = re[k], q = im[k];
                if (k & m) { re[k] = r * cz - q * sz; im[k] = q * cz + r * sz; }
                else       { re[k] = r * cz + q * sz; im[k] = q * cz - r * sz; }
            }
        }
#pragma unroll
        for (int w = 0; w < 3; ++w) {
            const int cm = 8 >> w, tm = 4 >> w;
#pragma unroll
            for (int b = 0; b < 16; ++b) {
                if ((b & cm) && !(b & tm)) {
                    const int j = b | tm;
                    float t = re[b]; re[b] = re[j]; re[j] = t;
                    t = im[b]; im[b] = im[j]; im[j] = t;
                }
            }
        }

        // ---- layers 1, 2 (layer-2 RZ dropped: probability-invariant) ----
#pragma unroll
        for (int l = 1; l < 3; ++l) {
#pragma unroll
            for (int w = 0; w < 4; ++w) {
                const int m = 8 >> w, g = l * 4 + w;
                const float cy = trig[g][0], sy = trig[g][1];
#pragma unroll
                for (int b = 0; b < 16; ++b) {
                    if (b & m) continue;
                    const int j = b | m;
                    const float r0 = re[b], r1 = re[j];
                    const float i0 = im[b], i1 = im[j];
                    re[b] = cy * r0 - sy * r1;  re[j] = sy * r0 + cy * r1;
                    im[b] = cy * i0 - sy * i1;  im[j] = sy * i0 + cy * i1;
                }
                if (l != 2) {
                    const float cz = trig[g][2], sz = trig[g][3];
#pragma unroll
                    for (int k = 0; k < 16; ++k) {
                        const float r = re[k], q = im[k];
                        if (k & m) { re[k] = r * cz - q * sz; im[k] = q * cz + r * sz; }
                        else       { re[k] = r * cz + q * sz; im[k] = q * cz - r * sz; }
                    }
                }
            }
#pragma unroll
            for (int w = 0; w < 3; ++w) {
                const int cm = 8 >> w, tm = 4 >> w;
#pragma unroll
                for (int b = 0; b < 16; ++b) {
                    if ((b & cm) && !(b & tm)) {
                        const int j = b | tm;
                        float t = re[b]; re[b] = re[j]; re[j] = t;
                        t = im[b]; im[b] = im[j]; im[j] = t;
                    }
                }
            }
        }

        float ev0 = 0.f, ev1 = 0.f, ev2 = 0.f, ev3 = 0.f;
#pragma unroll
        for (int k = 0; k < 16; ++k) {
            const float pk = re[k] * re[k] + im[k] * im[k];
            ev0 += (k & 8) ? -pk : pk;
            ev1 += (k & 4) ? -pk : pk;
            ev2 += (k & 2) ? -pk : pk;
            ev3 += (k & 1) ? -pk : pk;
        }
        bufA[tid][0] = ev0; bufA[tid][1] = ev1;
        bufA[tid][2] = ev2; bufA[tid][3] = ev3;
    }
    __syncthreads();

    // ---- invert evaluation map mode-by-mode ----
    // nodes {0, pi/2, pi} -> rows (1,1,0),(1,0,1),(1,-1,0);
    // Minv = [[.5,0,.5],[.5,0,-.5],[-.5,1,-.5]]
    const float Minv[3][3] = {{0.5f, 0.0f, 0.5f},
                              {0.5f, 0.0f, -0.5f},
                              {-0.5f, 1.0f, -0.5f}};
    const int strides[4] = {27, 9, 3, 1};
#pragma unroll
    for (int mo = 0; mo < 4; ++mo) {
        const int st = strides[mo];
        float (*src)[4] = (mo & 1) ? bufB : bufA;
        float (*dst)[4] = (mo & 1) ? bufA : bufB;
        for (int idx = tid; idx < 324; idx += blockDim.x) {
            const int w = idx & 3, pos = idx >> 2;
            const int dm = (pos / st) % 3;
            const int base = pos - dm * st;
            const float v = Minv[dm][0] * src[base][w]
                          + Minv[dm][1] * src[base + st][w]
                          + Minv[dm][2] * src[base + 2 * st][w];
            if (mo == 3) {
                const int half = (w >> 1);
                ws[half * 162 + pos * 2 + (w & 1)] = v;
            } else {
                dst[pos][w] = v;
            }
        }
        __syncthreads();
    }
}

__global__ __launch_bounds__(256) void vqc_main(const float* __restrict__ patch,
                                                const float* __restrict__ params,
                                                const float* __restrict__ ws,
                                                float* __restrict__ out,
                                                const int B) {
    const int i = blockIdx.x * blockDim.x + threadIdx.x;
    if (i >= B) return;

    const float4 p = reinterpret_cast<const float4*>(patch)[i];

    // batch-uniform param offsets via constant addrspace -> s_load
    cfloat* par = (cfloat*)(uintptr_t)params;

    float c0, s0, c1, s1, c2, s2, c3, s3;
    __sincosf(p.x + par[0], &s0, &c0);
    __sincosf(p.y + par[2], &s1, &c1);
    __sincosf(p.z + par[4], &s2, &c2);
    __sincosf(p.w + par[6], &s3, &c3);

    // basis outer products; index 0 == 1 (used implicitly)
    float v01[9], v23[9];
    v01[1] = c1;      v01[2] = s1;
    v01[3] = c0;   v01[4] = c0 * c1; v01[5] = c0 * s1;
    v01[6] = s0;   v01[7] = s0 * c1; v01[8] = s0 * s1;
    v23[1] = c3;      v23[2] = s3;
    v23[3] = c2;   v23[4] = c2 * c3; v23[5] = c2 * s3;
    v23[6] = s2;   v23[7] = s2 * c3; v23[8] = s2 * s3;

    // T pairs via constant addrspace -> uniform s_load_dwordx2, SGPR operands
    cv2f* TA = (cv2f*)(uintptr_t)ws;          // (T0,T1)[pos]
    cv2f* TB = (cv2f*)(uintptr_t)(ws + 162);  // (T2,T3)[pos]

    v2f o01, o23;
#pragma unroll
    for (int a = 0; a < 9; ++a) {
        v2f y01 = TA[9 * a];      // b = 0 term: v23[0] == 1
        v2f y23 = TB[9 * a];
#pragma unroll
        for (int b = 1; b < 9; ++b) {
            y01 += TA[9 * a + b] * v23[b];   // packed FMA, SGPR coefficient
            y23 += TB[9 * a + b] * v23[b];
        }
        if (a == 0) { o01 = y01; o23 = y23; }      // v01[0] == 1
        else        { o01 += v01[a] * y01; o23 += v01[a] * y23; }
    }

    reinterpret_cast<float4*>(out)[i] = make_float4(o01.x, o01.y, o23.x, o23.y);
}

extern "C" void kernel_launch(void* const* d_in, const int* in_sizes, int n_in,
                              void* d_out, int out_size, void* d_ws, size_t ws_size,
                              hipStream_t stream) {
    const float* patch  = (const float*)d_in[0];
    const float* params = (const float*)d_in[1];
    float* out = (float*)d_out;
    float* ws  = (float*)d_ws;
    const int B = in_sizes[0] / 4;

    vqc_setup<<<1, 128, 0, stream>>>(params, ws);

    const int block = 256;
    const int grid = (B + block - 1) / block;
    vqc_main<<<grid, block, 0, stream>>>(patch, params, ws, out, B);
}